// Round 1
// baseline (925.629 us; speedup 1.0000x reference)
//
#include <hip/hip_runtime.h>

#define EPS 1e-5f
constexpr int HD = 128;   // node feature / hidden dim
constexpr int FC = 64;    // fc hidden dim

// ------------------- preprocessing: degree, CSR build -------------------

__global__ void k_count(const int* __restrict__ dst, int* __restrict__ cnt, int E){
  int e = blockIdx.x*256 + threadIdx.x;
  if (e < E) atomicAdd(&cnt[dst[e]], 1);
}

__global__ void k_dis(const int* __restrict__ cnt, float* __restrict__ dis, int N){
  int i = blockIdx.x*256 + threadIdx.x;
  if (i < N) dis[i] = rsqrtf((float)cnt[i] + 1.0f);   // +1 self-loop; deg>=1
}

// single-block inclusive scan (wave-scan + wave-total scan), produces rowptr[0..N]
__global__ __launch_bounds__(1024) void k_scan(const int* __restrict__ cnt,
                                               int* __restrict__ rowptr, int n){
  __shared__ int wtot[16];
  __shared__ int carry;
  int tid = threadIdx.x, lane = tid & 63, wid = tid >> 6;
  if (tid == 0){ carry = 0; rowptr[0] = 0; }
  __syncthreads();
  for (int base = 0; base < n; base += 1024){
    int idx = base + tid;
    int v = (idx < n) ? cnt[idx] : 0;
    int incl = v;
    #pragma unroll
    for (int o = 1; o < 64; o <<= 1){
      int t = __shfl_up(incl, o, 64);
      if (lane >= o) incl += t;
    }
    if (lane == 63) wtot[wid] = incl;
    __syncthreads();
    if (wid == 0){
      int w = (lane < 16) ? wtot[lane] : 0;
      #pragma unroll
      for (int o = 1; o < 16; o <<= 1){
        int t = __shfl_up(w, o, 64);
        if (lane >= o) w += t;
      }
      if (lane < 16) wtot[lane] = w;
    }
    __syncthreads();
    int off = carry + (wid ? wtot[wid-1] : 0);
    if (idx < n) rowptr[idx+1] = off + incl;
    int total = wtot[15];
    __syncthreads();
    if (tid == 0) carry += total;
    __syncthreads();
  }
}

__global__ void k_cursor(const int* __restrict__ rowptr, int* __restrict__ cursor, int N){
  int i = blockIdx.x*256 + threadIdx.x;
  if (i < N) cursor[i] = rowptr[i];
}

__global__ void k_fill(const int* __restrict__ src, const int* __restrict__ dst,
                       const float* __restrict__ dis, int* __restrict__ cursor,
                       int* __restrict__ csrc, float* __restrict__ cw, int E){
  int e = blockIdx.x*256 + threadIdx.x;
  if (e >= E) return;
  int s = src[e], d = dst[e];
  int pos = atomicAdd(&cursor[d], 1);
  csrc[pos] = s;
  cw[pos] = dis[s]*dis[d];
}

// ------------------- GEMM: [N,128] @ [128,128], fp32 -------------------
// W staged in LDS (64KB). 256 threads: tx=col-group (4 cols), ty=row-group (4 rows).
// A reads are wave-broadcast (2 addrs/wave), L1-cached.
__global__ __launch_bounds__(256) void k_gemm(const float* __restrict__ A,
                                              const float* __restrict__ W,
                                              float* __restrict__ O, int n){
  __shared__ float Wl[HD*HD];
  int tid = threadIdx.x;
  for (int i = tid*4; i < HD*HD; i += 256*4)
    *(float4*)&Wl[i] = *(const float4*)&W[i];
  __syncthreads();
  int tx = tid & 31, ty = tid >> 5;
  int r0 = blockIdx.x*32 + ty*4;
  float4 acc[4] = {};
  for (int k = 0; k < HD; k += 4){
    float4 b0 = *(float4*)&Wl[(k+0)*HD + tx*4];
    float4 b1 = *(float4*)&Wl[(k+1)*HD + tx*4];
    float4 b2 = *(float4*)&Wl[(k+2)*HD + tx*4];
    float4 b3 = *(float4*)&Wl[(k+3)*HD + tx*4];
    #pragma unroll
    for (int r = 0; r < 4; ++r){
      int row = r0 + r; if (row > n-1) row = n-1;   // clamp loads, guard stores
      float4 a = *(const float4*)&A[(size_t)row*HD + k];
      acc[r].x += a.x*b0.x + a.y*b1.x + a.z*b2.x + a.w*b3.x;
      acc[r].y += a.x*b0.y + a.y*b1.y + a.z*b2.y + a.w*b3.y;
      acc[r].z += a.x*b0.z + a.y*b1.z + a.z*b2.z + a.w*b3.z;
      acc[r].w += a.x*b0.w + a.y*b1.w + a.z*b2.w + a.w*b3.w;
    }
  }
  #pragma unroll
  for (int r = 0; r < 4; ++r){
    int row = r0 + r;
    if (row < n) *(float4*)&O[(size_t)row*HD + tx*4] = acc[r];
  }
}

// ------------------- edge aggregation: gather over CSR -------------------
// one block (128 thr) per node; acc init = self-loop term; coalesced 512B row reads
__global__ __launch_bounds__(128) void k_gather(const float* __restrict__ hw,
                                                const int* __restrict__ rowptr,
                                                const int* __restrict__ csrc,
                                                const float* __restrict__ cw,
                                                const float* __restrict__ dis,
                                                float* __restrict__ agg, int N){
  int i = blockIdx.x;
  int c = threadIdx.x;
  float sn = dis[i]; sn *= sn;
  float acc = hw[(size_t)i*HD + c] * sn;
  int e0 = rowptr[i], e1 = rowptr[i+1];
  for (int e = e0; e < e1; ++e){
    int s = csrc[e];
    float w = cw[e];
    acc += hw[(size_t)s*HD + c] * w;
  }
  agg[(size_t)i*HD + c] = acc;
}

// ------------------- BatchNorm (training stats) + ReLU -------------------

__global__ __launch_bounds__(128) void k_stats(const float* __restrict__ t,
                                               float* __restrict__ sums, int N){
  int c = threadIdx.x;
  float s = 0.f, q = 0.f;
  for (int i = blockIdx.x; i < N; i += gridDim.x){
    float v = t[(size_t)i*HD + c];
    s += v; q += v*v;
  }
  atomicAdd(&sums[c], s);
  atomicAdd(&sums[HD + c], q);
}

__global__ void k_finalize(const float* __restrict__ sums, const float* __restrict__ g,
                           const float* __restrict__ be, float* __restrict__ ab, float invN){
  int c = threadIdx.x;                       // 128
  float m = sums[c] * invN;
  float v = fmaxf(sums[HD + c] * invN - m*m, 0.f);
  float inv = rsqrtf(v + EPS);
  float A = g[c] * inv;
  ab[c] = A;
  ab[HD + c] = be[c] - m * A;
}

__global__ void k_normrelu(float* __restrict__ t, const float* __restrict__ ab, int total4){
  int idx = blockIdx.x*256 + threadIdx.x;
  if (idx >= total4) return;
  int c4 = idx & 31;                         // 32 float4 per 128-col row
  const float4* A4 = (const float4*)ab;
  float4 a = A4[c4];
  float4 b = A4[32 + c4];
  float4 v = ((float4*)t)[idx];
  v.x = fmaxf(v.x*a.x + b.x, 0.f);
  v.y = fmaxf(v.y*a.y + b.y, 0.f);
  v.z = fmaxf(v.z*a.z + b.z, 0.f);
  v.w = fmaxf(v.w*a.w + b.w, 0.f);
  ((float4*)t)[idx] = v;
}

// ------------------- mean pool per graph (batch is sorted) -------------------

__global__ void k_cnt(const int* __restrict__ batch, float* __restrict__ cntf, int N){
  int i = blockIdx.x*256 + threadIdx.x;
  if (i < N) atomicAdd(&cntf[batch[i]], 1.0f);
}

// register-accumulate runs of equal batch id, flush on change -> few atomics
__global__ __launch_bounds__(128) void k_pool(const float* __restrict__ h,
                                              const int* __restrict__ batch,
                                              float* __restrict__ pooled, int N){
  int c = threadIdx.x;
  int start = blockIdx.x * 128;
  if (start >= N) return;
  int end = min(start + 128, N);
  int cur = batch[start];
  float acc = 0.f;
  for (int i = start; i < end; ++i){
    int b = batch[i];
    if (b != cur){ atomicAdd(&pooled[(size_t)cur*HD + c], acc); acc = 0.f; cur = b; }
    acc += h[(size_t)i*HD + c];
  }
  atomicAdd(&pooled[(size_t)cur*HD + c], acc);
}

// ------------------- FC head -------------------

__global__ __launch_bounds__(64) void k_fc1(const float* __restrict__ pooled,
                                            const float* __restrict__ cntf,
                                            const float* __restrict__ W,
                                            const float* __restrict__ b,
                                            float* __restrict__ z, int G){
  int g = blockIdx.x, j = threadIdx.x;
  float inv = 1.0f / fmaxf(cntf[g], 1.0f);
  float acc = 0.f;
  for (int k = 0; k < HD; ++k)
    acc += pooled[(size_t)g*HD + k] * W[k*FC + j];
  z[(size_t)g*FC + j] = acc * inv + b[j];
}

__global__ __launch_bounds__(64) void k_stats2(const float* __restrict__ z,
                                               float* __restrict__ sums, int G){
  int c = threadIdx.x;
  float s = 0.f, q = 0.f;
  for (int i = blockIdx.x; i < G; i += gridDim.x){
    float v = z[(size_t)i*FC + c]; s += v; q += v*v;
  }
  atomicAdd(&sums[c], s);
  atomicAdd(&sums[FC + c], q);
}

__global__ void k_finalize2(const float* __restrict__ sums, const float* __restrict__ g,
                            const float* __restrict__ be, float* __restrict__ ab, float invG){
  int c = threadIdx.x;                       // 64
  float m = sums[c]*invG;
  float v = fmaxf(sums[FC+c]*invG - m*m, 0.f);
  float inv = rsqrtf(v + EPS);
  float A = g[c]*inv;
  ab[c] = A; ab[FC+c] = be[c] - m*A;
}

__global__ __launch_bounds__(64) void k_final(const float* __restrict__ z,
                                              const float* __restrict__ ab,
                                              const float* __restrict__ w2,
                                              const float* __restrict__ b2,
                                              float* __restrict__ out, int G){
  int g = blockIdx.x, c = threadIdx.x;
  float v = fmaxf(z[(size_t)g*FC + c]*ab[c] + ab[FC+c], 0.f);
  v *= w2[c];
  #pragma unroll
  for (int o = 32; o > 0; o >>= 1) v += __shfl_down(v, o, 64);
  if (c == 0) out[g] = v + b2[0];
}

// ------------------- launch -------------------

extern "C" void kernel_launch(void* const* d_in, const int* in_sizes, int n_in,
                              void* d_out, int out_size, void* d_ws, size_t ws_size,
                              hipStream_t stream){
  const float* x    = (const float*)d_in[0];
  const int*   ei   = (const int*)d_in[1];
  const int*   batch= (const int*)d_in[2];
  const float* W1 = (const float*)d_in[3];
  const float* g1 = (const float*)d_in[5];
  const float* be1= (const float*)d_in[6];
  const float* W2 = (const float*)d_in[7];
  const float* g2 = (const float*)d_in[9];
  const float* be2= (const float*)d_in[10];
  const float* W3 = (const float*)d_in[11];
  const float* g3 = (const float*)d_in[13];
  const float* be3= (const float*)d_in[14];
  const float* fcW1 = (const float*)d_in[15];
  const float* fcb1 = (const float*)d_in[16];
  const float* fcg1 = (const float*)d_in[17];
  const float* fcbe1= (const float*)d_in[18];
  const float* fcW2 = (const float*)d_in[19];
  const float* fcb2 = (const float*)d_in[20];
  float* out = (float*)d_out;

  const int N = in_sizes[0] / HD;      // 50000
  const int E = in_sizes[1] / 2;       // 800000
  const int G = out_size;              // 500

  const int* esrc = ei;
  const int* edst = ei + E;

  // workspace carve-up (~59 MB total); re-poisoned every call -> everything
  // below is fully (re)written before being read.
  char* p = (char*)d_ws;
  auto alloc = [&](size_t bytes)->void*{
    void* r = (void*)p; p += (bytes + 255) & ~(size_t)255; return r;
  };
  int*   cnt    = (int*)  alloc((size_t)N*4);
  int*   rowptr = (int*)  alloc((size_t)(N+1)*4);
  int*   cursor = (int*)  alloc((size_t)N*4);
  int*   csrc   = (int*)  alloc((size_t)E*4);
  float* cw     = (float*)alloc((size_t)E*4);
  float* dis    = (float*)alloc((size_t)N*4);
  float* HWb    = (float*)alloc((size_t)N*HD*4);
  float* AGG    = (float*)alloc((size_t)N*HD*4);
  float* sums   = (float*)alloc(2*HD*4);
  float* ab     = (float*)alloc(2*HD*4);
  float* pooled = (float*)alloc((size_t)G*HD*4);
  float* cntf   = (float*)alloc((size_t)G*4);
  float* zbuf   = (float*)alloc((size_t)G*FC*4);
  float* sums2  = (float*)alloc(2*FC*4);
  float* ab2    = (float*)alloc(2*FC*4);

  int eb = (E + 255)/256, nb = (N + 255)/256;

  hipMemsetAsync(cnt, 0, (size_t)N*4, stream);
  k_count <<<eb, 256, 0, stream>>>(edst, cnt, E);
  k_dis   <<<nb, 256, 0, stream>>>(cnt, dis, N);
  k_scan  <<<1, 1024, 0, stream>>>(cnt, rowptr, N);
  k_cursor<<<nb, 256, 0, stream>>>(rowptr, cursor, N);
  k_fill  <<<eb, 256, 0, stream>>>(esrc, edst, dis, cursor, csrc, cw, E);

  const float* Ws[3]  = {W1, W2, W3};
  const float* gs[3]  = {g1, g2, g3};
  const float* bes[3] = {be1, be2, be3};
  const float* in = x;
  int gemmBlocks = (N + 31)/32;
  int nr4 = (N*HD/4 + 255)/256;
  for (int l = 0; l < 3; ++l){
    k_gemm  <<<gemmBlocks, 256, 0, stream>>>(in, Ws[l], HWb, N);
    k_gather<<<N, 128, 0, stream>>>(HWb, rowptr, csrc, cw, dis, AGG, N);
    hipMemsetAsync(sums, 0, 2*HD*4, stream);
    k_stats   <<<256, 128, 0, stream>>>(AGG, sums, N);
    k_finalize<<<1, HD, 0, stream>>>(sums, gs[l], bes[l], ab, 1.0f/(float)N);
    k_normrelu<<<nr4, 256, 0, stream>>>(AGG, ab, N*HD/4);
    in = AGG;
  }

  hipMemsetAsync(pooled, 0, (size_t)G*HD*4, stream);
  hipMemsetAsync(cntf,   0, (size_t)G*4,    stream);
  k_cnt <<<nb, 256, 0, stream>>>(batch, cntf, N);
  k_pool<<<(N+127)/128, 128, 0, stream>>>(AGG, batch, pooled, N);
  k_fc1 <<<G, FC, 0, stream>>>(pooled, cntf, fcW1, fcb1, zbuf, G);
  hipMemsetAsync(sums2, 0, 2*FC*4, stream);
  k_stats2   <<<64, FC, 0, stream>>>(zbuf, sums2, G);
  k_finalize2<<<1, FC, 0, stream>>>(sums2, fcg1, fcbe1, ab2, 1.0f/(float)G);
  k_final    <<<G, FC, 0, stream>>>(zbuf, ab2, fcW2, fcb2, out, G);
}

// Round 2
// 572.149 us; speedup vs baseline: 1.6178x; 1.6178x over previous
//
#include <hip/hip_runtime.h>

#define EPS 1e-5f
constexpr int HD = 128;   // node feature / hidden dim
constexpr int FCD = 64;   // fc hidden dim

typedef __attribute__((ext_vector_type(8))) short short8;
typedef __attribute__((ext_vector_type(4))) float floatx4;

// ---------- bf16 helpers (RNE pack, cheap unpack) ----------
__device__ inline ushort f2bf(float f){
  union{float f; unsigned u;} v; v.f = f;
  unsigned r = v.u + 0x7FFFu + ((v.u >> 16) & 1u);
  return (ushort)(r >> 16);
}
__device__ inline float bflo(unsigned u){ union{unsigned i; float f;} v; v.i = u << 16;        return v.f; }
__device__ inline float bfhi(unsigned u){ union{unsigned i; float f;} v; v.i = u & 0xFFFF0000u; return v.f; }

// ------------------- preprocessing -------------------

__global__ void k_count(const int* __restrict__ dst, int* __restrict__ cnt, int E){
  int e = blockIdx.x*256 + threadIdx.x;
  if (e < E) atomicAdd(&cnt[dst[e]], 1);
}

// single-block scan: produces rowptr[0..N], cursor[i]=rowptr[i], dis[i]=rsqrt(deg+1)
__global__ __launch_bounds__(1024) void k_scan(const int* __restrict__ cnt,
                                               int* __restrict__ rowptr,
                                               int* __restrict__ cursor,
                                               float* __restrict__ dis, int n){
  __shared__ int wtot[16];
  __shared__ int carry;
  int tid = threadIdx.x, lane = tid & 63, wid = tid >> 6;
  if (tid == 0){ carry = 0; rowptr[0] = 0; }
  __syncthreads();
  for (int base = 0; base < n; base += 1024){
    int idx = base + tid;
    int v = (idx < n) ? cnt[idx] : 0;
    int incl = v;
    #pragma unroll
    for (int o = 1; o < 64; o <<= 1){
      int t = __shfl_up(incl, o, 64);
      if (lane >= o) incl += t;
    }
    if (lane == 63) wtot[wid] = incl;
    __syncthreads();
    if (wid == 0){
      int w = (lane < 16) ? wtot[lane] : 0;
      #pragma unroll
      for (int o = 1; o < 16; o <<= 1){
        int t = __shfl_up(w, o, 64);
        if (lane >= o) w += t;
      }
      if (lane < 16) wtot[lane] = w;
    }
    __syncthreads();
    int off = carry + (wid ? wtot[wid-1] : 0);
    if (idx < n){
      rowptr[idx+1] = off + incl;
      cursor[idx]   = off + incl - v;
      dis[idx]      = rsqrtf((float)v + 1.0f);
    }
    int total = wtot[15];
    __syncthreads();
    if (tid == 0) carry += total;
    __syncthreads();
  }
}

__global__ void k_fill(const int* __restrict__ src, const int* __restrict__ dst,
                       const float* __restrict__ dis, int* __restrict__ cursor,
                       int2* __restrict__ edata, int E){
  int e = blockIdx.x*256 + threadIdx.x;
  if (e >= E) return;
  int s = src[e], d = dst[e];
  int pos = atomicAdd(&cursor[d], 1);
  edata[pos] = make_int2(s, __float_as_int(dis[s]*dis[d]));
}

// pack W [128,128] fp32 -> fragment-major bf16 for mfma_f32_16x16x32_bf16 B-operand
// B-frag: lane = quad*16 + col holds W[kb*32+quad*8+j][nt*16+col], j=0..7 contiguous
__global__ void k_prepW(const float* __restrict__ W1, const float* __restrict__ W2,
                        const float* __restrict__ W3, ushort* __restrict__ Wf){
  const float* Ws[3] = {W1, W2, W3};
  int l = blockIdx.y;
  int idx = blockIdx.x*256 + threadIdx.x;        // 0..16383
  int k = idx >> 7, n = idx & 127;
  float w = Ws[l][idx];
  int kb = k >> 5, q = (k >> 3) & 3, j = k & 7;
  int nt = n >> 4, col = n & 15;
  Wf[(size_t)l*16384 + (((size_t)(kb*8 + nt)*64 + q*16 + col)*8 + j)] = f2bf(w);
}

// ------------------- GEMM: bf16 MFMA, fused BN-affine+ReLU on A -------------------
// block 256 thr = 4 waves; wave computes 16 rows x 128 cols (8 n-tiles).
// MODE 0: A=x, plain cvt. MODE 1: A=AGG, apply a[k]*v+b[k], relu (a,b from sums of prev layer).
template<int MODE>
__global__ __launch_bounds__(256) void k_gemm(const float* __restrict__ A,
                                              const ushort* __restrict__ Wf,
                                              const float* __restrict__ sums,
                                              const float* __restrict__ g,
                                              const float* __restrict__ be,
                                              ushort* __restrict__ O, int n, float invN){
  __shared__ float aL[HD], bL[HD];
  int tid = threadIdx.x;
  if (MODE){
    if (tid < HD){
      float m = sums[tid]*invN;
      float var = fmaxf(sums[HD+tid]*invN - m*m, 0.f);
      float Ac = g[tid]*rsqrtf(var + EPS);
      aL[tid] = Ac; bL[tid] = be[tid] - m*Ac;
    }
    __syncthreads();
  }
  int lane = tid & 63, wave = tid >> 6;
  int quad = lane >> 4, r16 = lane & 15;
  int row = blockIdx.x*64 + wave*16 + r16;
  int rowc = min(row, n-1);
  const float* Arow = A + (size_t)rowc*HD;
  floatx4 acc[8] = {};
  #pragma unroll
  for (int kb = 0; kb < 4; ++kb){
    int k0 = kb*32 + quad*8;
    float4 x0 = *(const float4*)(Arow + k0);
    float4 x1 = *(const float4*)(Arow + k0 + 4);
    if (MODE){
      float4 ca0 = *(const float4*)(aL + k0), ca1 = *(const float4*)(aL + k0 + 4);
      float4 cb0 = *(const float4*)(bL + k0), cb1 = *(const float4*)(bL + k0 + 4);
      x0.x = fmaxf(x0.x*ca0.x + cb0.x, 0.f);
      x0.y = fmaxf(x0.y*ca0.y + cb0.y, 0.f);
      x0.z = fmaxf(x0.z*ca0.z + cb0.z, 0.f);
      x0.w = fmaxf(x0.w*ca0.w + cb0.w, 0.f);
      x1.x = fmaxf(x1.x*ca1.x + cb1.x, 0.f);
      x1.y = fmaxf(x1.y*ca1.y + cb1.y, 0.f);
      x1.z = fmaxf(x1.z*ca1.z + cb1.z, 0.f);
      x1.w = fmaxf(x1.w*ca1.w + cb1.w, 0.f);
    }
    short8 af;
    af[0] = (short)f2bf(x0.x); af[1] = (short)f2bf(x0.y);
    af[2] = (short)f2bf(x0.z); af[3] = (short)f2bf(x0.w);
    af[4] = (short)f2bf(x1.x); af[5] = (short)f2bf(x1.y);
    af[6] = (short)f2bf(x1.z); af[7] = (short)f2bf(x1.w);
    const ushort* wp = Wf + ((size_t)(kb*8)*64 + lane)*8;
    #pragma unroll
    for (int nt = 0; nt < 8; ++nt){
      short8 bf = *(const short8*)(wp + (size_t)nt*64*8);
      acc[nt] = __builtin_amdgcn_mfma_f32_16x16x32_bf16(af, bf, acc[nt], 0, 0, 0);
    }
  }
  int rbase = blockIdx.x*64 + wave*16 + quad*4;
  #pragma unroll
  for (int nt = 0; nt < 8; ++nt){
    #pragma unroll
    for (int r = 0; r < 4; ++r){
      int rr = rbase + r;
      if (rr < n) O[(size_t)rr*HD + nt*16 + r16] = f2bf(acc[nt][r]);
    }
  }
}

// ------------------- edge aggregation: bf16 gather over CSR -------------------
// 16 lanes per node (16B/lane), 16 nodes per 256-thr block, edge loop unrolled x4.
// block 0 also zeroes sums[] for this layer's stats pass.
__global__ __launch_bounds__(256) void k_gather(const ushort* __restrict__ hw,
                                                const int* __restrict__ rowptr,
                                                const int2* __restrict__ edata,
                                                const float* __restrict__ dis,
                                                float* __restrict__ agg,
                                                float* __restrict__ sums, int N){
  if (blockIdx.x == 0) sums[threadIdx.x] = 0.f;   // 256 floats, before stats kernel
  int grp = threadIdx.x >> 4, j = threadIdx.x & 15;
  int i = blockIdx.x*16 + grp;
  if (i >= N) return;
  float sn = dis[i]; sn *= sn;
  const uint4* self = (const uint4*)(hw + (size_t)i*HD);
  uint4 q = self[j];
  float a0 = bflo(q.x)*sn, a1 = bfhi(q.x)*sn;
  float a2 = bflo(q.y)*sn, a3 = bfhi(q.y)*sn;
  float a4 = bflo(q.z)*sn, a5 = bfhi(q.z)*sn;
  float a6 = bflo(q.w)*sn, a7 = bfhi(q.w)*sn;
  int e = rowptr[i], e1 = rowptr[i+1];
  #define ACC8(Q, W) \
    a0 = fmaf(bflo(Q.x), W, a0); a1 = fmaf(bfhi(Q.x), W, a1); \
    a2 = fmaf(bflo(Q.y), W, a2); a3 = fmaf(bfhi(Q.y), W, a3); \
    a4 = fmaf(bflo(Q.z), W, a4); a5 = fmaf(bfhi(Q.z), W, a5); \
    a6 = fmaf(bflo(Q.w), W, a6); a7 = fmaf(bfhi(Q.w), W, a7);
  for (; e + 4 <= e1; e += 4){
    int2 d0 = edata[e], d1 = edata[e+1], d2 = edata[e+2], d3 = edata[e+3];
    uint4 q0 = ((const uint4*)(hw + (size_t)d0.x*HD))[j];
    uint4 q1 = ((const uint4*)(hw + (size_t)d1.x*HD))[j];
    uint4 q2 = ((const uint4*)(hw + (size_t)d2.x*HD))[j];
    uint4 q3 = ((const uint4*)(hw + (size_t)d3.x*HD))[j];
    float w0 = __int_as_float(d0.y), w1 = __int_as_float(d1.y);
    float w2 = __int_as_float(d2.y), w3 = __int_as_float(d3.y);
    ACC8(q0, w0); ACC8(q1, w1); ACC8(q2, w2); ACC8(q3, w3);
  }
  for (; e < e1; ++e){
    int2 d = edata[e];
    uint4 qq = ((const uint4*)(hw + (size_t)d.x*HD))[j];
    float w = __int_as_float(d.y);
    ACC8(qq, w);
  }
  #undef ACC8
  float* out = agg + (size_t)i*HD + j*8;
  *(float4*)out       = make_float4(a0, a1, a2, a3);
  *(float4*)(out + 4) = make_float4(a4, a5, a6, a7);
}

// ------------------- BN stats (column sums / sumsq) -------------------

__global__ __launch_bounds__(128) void k_stats(const float* __restrict__ t,
                                               float* __restrict__ sums, int N){
  int c = threadIdx.x;
  float s = 0.f, q = 0.f;
  for (int i = blockIdx.x; i < N; i += gridDim.x){
    float v = t[(size_t)i*HD + c];
    s += v; q += v*v;
  }
  atomicAdd(&sums[c], s);
  atomicAdd(&sums[HD + c], q);
}

// ------------------- mean pool (fused layer-3 BN+ReLU, fused counts) -------------------

__global__ __launch_bounds__(128) void k_pool(const float* __restrict__ h,
                                              const int* __restrict__ batch,
                                              const float* __restrict__ sums,
                                              const float* __restrict__ g,
                                              const float* __restrict__ be,
                                              float* __restrict__ pooled,
                                              float* __restrict__ cntf, int N, float invN){
  int c = threadIdx.x;
  float m = sums[c]*invN;
  float var = fmaxf(sums[HD+c]*invN - m*m, 0.f);
  float a = g[c]*rsqrtf(var + EPS);
  float b = be[c] - m*a;
  int start = blockIdx.x * 128;
  if (start >= N) return;
  int end = min(start + 128, N);
  int cur = batch[start];
  float acc = 0.f; int run = 0;
  for (int i = start; i < end; ++i){
    int bb = batch[i];
    if (bb != cur){
      atomicAdd(&pooled[(size_t)cur*HD + c], acc);
      if (c == 0) atomicAdd(&cntf[cur], (float)run);
      acc = 0.f; run = 0; cur = bb;
    }
    acc += fmaxf(h[(size_t)i*HD + c]*a + b, 0.f);
    run++;
  }
  atomicAdd(&pooled[(size_t)cur*HD + c], acc);
  if (c == 0) atomicAdd(&cntf[cur], (float)run);
}

// ------------------- FC head -------------------

__global__ __launch_bounds__(64) void k_fc1(const float* __restrict__ pooled,
                                            const float* __restrict__ cntf,
                                            const float* __restrict__ W,
                                            const float* __restrict__ b,
                                            float* __restrict__ z,
                                            float* __restrict__ sums2, int G){
  int g = blockIdx.x, j = threadIdx.x;
  if (g == 0){ sums2[j] = 0.f; sums2[FCD + j] = 0.f; }   // before k_stats2
  float inv = 1.0f / fmaxf(cntf[g], 1.0f);
  float acc = 0.f;
  for (int k = 0; k < HD; ++k)
    acc += pooled[(size_t)g*HD + k] * W[k*FCD + j];
  z[(size_t)g*FCD + j] = acc * inv + b[j];
}

__global__ __launch_bounds__(64) void k_stats2(const float* __restrict__ z,
                                               float* __restrict__ sums2, int G){
  int c = threadIdx.x;
  float s = 0.f, q = 0.f;
  for (int i = blockIdx.x; i < G; i += gridDim.x){
    float v = z[(size_t)i*FCD + c]; s += v; q += v*v;
  }
  atomicAdd(&sums2[c], s);
  atomicAdd(&sums2[FCD + c], q);
}

__global__ __launch_bounds__(64) void k_final(const float* __restrict__ z,
                                              const float* __restrict__ sums2,
                                              const float* __restrict__ g,
                                              const float* __restrict__ be,
                                              const float* __restrict__ w2,
                                              const float* __restrict__ b2,
                                              float* __restrict__ out, int G, float invG){
  int gg = blockIdx.x, c = threadIdx.x;
  float m = sums2[c]*invG;
  float var = fmaxf(sums2[FCD+c]*invG - m*m, 0.f);
  float A = g[c]*rsqrtf(var + EPS);
  float B = be[c] - m*A;
  float v = fmaxf(z[(size_t)gg*FCD + c]*A + B, 0.f) * w2[c];
  #pragma unroll
  for (int o = 32; o > 0; o >>= 1) v += __shfl_down(v, o, 64);
  if (c == 0) out[gg] = v + b2[0];
}

// ------------------- launch -------------------

extern "C" void kernel_launch(void* const* d_in, const int* in_sizes, int n_in,
                              void* d_out, int out_size, void* d_ws, size_t ws_size,
                              hipStream_t stream){
  const float* x    = (const float*)d_in[0];
  const int*   ei   = (const int*)d_in[1];
  const int*   batch= (const int*)d_in[2];
  const float* W1 = (const float*)d_in[3];
  const float* g1 = (const float*)d_in[5];
  const float* be1= (const float*)d_in[6];
  const float* W2 = (const float*)d_in[7];
  const float* g2 = (const float*)d_in[9];
  const float* be2= (const float*)d_in[10];
  const float* W3 = (const float*)d_in[11];
  const float* g3 = (const float*)d_in[13];
  const float* be3= (const float*)d_in[14];
  const float* fcW1 = (const float*)d_in[15];
  const float* fcb1 = (const float*)d_in[16];
  const float* fcg1 = (const float*)d_in[17];
  const float* fcbe1= (const float*)d_in[18];
  const float* fcW2 = (const float*)d_in[19];
  const float* fcb2 = (const float*)d_in[20];
  float* out = (float*)d_out;

  const int N = in_sizes[0] / HD;      // 50000
  const int E = in_sizes[1] / 2;       // 800000
  const int G = out_size;              // 500

  const int* esrc = ei;
  const int* edst = ei + E;

  char* p = (char*)d_ws;
  auto alloc = [&](size_t bytes)->void*{
    void* r = (void*)p; p += (bytes + 255) & ~(size_t)255; return r;
  };
  int*    cnt    = (int*)   alloc((size_t)N*4);
  int*    rowptr = (int*)   alloc((size_t)(N+1)*4);
  int*    cursor = (int*)   alloc((size_t)N*4);
  int2*   edata  = (int2*)  alloc((size_t)E*8);
  float*  dis    = (float*) alloc((size_t)N*4);
  ushort* HWb    = (ushort*)alloc((size_t)N*HD*2);
  float*  AGG    = (float*) alloc((size_t)N*HD*4);
  ushort* Wf     = (ushort*)alloc((size_t)3*HD*HD*2);
  float*  sums   = (float*) alloc(2*HD*4);
  float*  pooled = (float*) alloc(((size_t)G*HD + G)*4);  // pooled | cntf contiguous
  float*  cntf   = pooled + (size_t)G*HD;
  float*  zbuf   = (float*) alloc((size_t)G*FCD*4);
  float*  sums2  = (float*) alloc(2*FCD*4);

  int eb = (E + 255)/256, nb = (N + 255)/256;
  float invN = 1.0f/(float)N, invG = 1.0f/(float)G;

  // preprocessing
  hipMemsetAsync(cnt, 0, (size_t)N*4, stream);
  k_count<<<eb, 256, 0, stream>>>(edst, cnt, E);
  k_scan <<<1, 1024, 0, stream>>>(cnt, rowptr, cursor, dis, N);
  k_fill <<<eb, 256, 0, stream>>>(esrc, edst, dis, cursor, edata, E);
  k_prepW<<<dim3(64,3), 256, 0, stream>>>(W1, W2, W3, Wf);

  int gemmBlocks = (N + 63)/64;
  int gatherBlocks = (N + 15)/16;

  // layer 1
  k_gemm<0><<<gemmBlocks, 256, 0, stream>>>(x,   Wf,          nullptr, nullptr, nullptr, HWb, N, invN);
  k_gather <<<gatherBlocks, 256, 0, stream>>>(HWb, rowptr, edata, dis, AGG, sums, N);
  k_stats  <<<256, 128, 0, stream>>>(AGG, sums, N);
  // layer 2 (BN1+ReLU fused into A-load)
  k_gemm<1><<<gemmBlocks, 256, 0, stream>>>(AGG, Wf + 16384,  sums, g1, be1, HWb, N, invN);
  k_gather <<<gatherBlocks, 256, 0, stream>>>(HWb, rowptr, edata, dis, AGG, sums, N);
  k_stats  <<<256, 128, 0, stream>>>(AGG, sums, N);
  // layer 3 (BN2+ReLU fused into A-load)
  k_gemm<1><<<gemmBlocks, 256, 0, stream>>>(AGG, Wf + 32768,  sums, g2, be2, HWb, N, invN);
  k_gather <<<gatherBlocks, 256, 0, stream>>>(HWb, rowptr, edata, dis, AGG, sums, N);
  k_stats  <<<256, 128, 0, stream>>>(AGG, sums, N);

  // pool (BN3+ReLU fused) + head
  hipMemsetAsync(pooled, 0, ((size_t)G*HD + G)*4, stream);
  k_pool  <<<(N+127)/128, 128, 0, stream>>>(AGG, batch, sums, g3, be3, pooled, cntf, N, invN);
  k_fc1   <<<G, FCD, 0, stream>>>(pooled, cntf, fcW1, fcb1, zbuf, sums2, G);
  k_stats2<<<64, FCD, 0, stream>>>(zbuf, sums2, G);
  k_final <<<G, FCD, 0, stream>>>(zbuf, sums2, fcg1, fcbe1, fcW2, fcb2, out, G, invG);
}

// Round 3
// 435.438 us; speedup vs baseline: 2.1257x; 1.3140x over previous
//
#include <hip/hip_runtime.h>

#define EPS 1e-5f
constexpr int HD = 128;   // node feature / hidden dim
constexpr int FCD = 64;   // fc hidden dim

typedef __attribute__((ext_vector_type(8))) short short8;
typedef __attribute__((ext_vector_type(4))) float floatx4;

// ---------- bf16 helpers (RNE pack, cheap unpack) ----------
__device__ inline ushort f2bf(float f){
  union{float f; unsigned u;} v; v.f = f;
  unsigned r = v.u + 0x7FFFu + ((v.u >> 16) & 1u);
  return (ushort)(r >> 16);
}
__device__ inline float bflo(unsigned u){ union{unsigned i; float f;} v; v.i = u << 16;        return v.f; }
__device__ inline float bfhi(unsigned u){ union{unsigned i; float f;} v; v.i = u & 0xFFFF0000u; return v.f; }

// ------------------- preprocessing -------------------

__global__ void k_count(const int* __restrict__ dst, int* __restrict__ cnt, int E){
  int e = blockIdx.x*256 + threadIdx.x;
  if (e < E) atomicAdd(&cnt[dst[e]], 1);
}

// single-block scan, 4 elements/thread: rowptr[0..N], cursor[i]=rowptr[i], dis[i]=rsqrt(deg+1)
__global__ __launch_bounds__(1024) void k_scan(const int* __restrict__ cnt,
                                               int* __restrict__ rowptr,
                                               int* __restrict__ cursor,
                                               float* __restrict__ dis, int n){
  __shared__ int wtot[16];
  __shared__ int carry;
  int tid = threadIdx.x, lane = tid & 63, wid = tid >> 6;
  if (tid == 0){ carry = 0; rowptr[0] = 0; }
  __syncthreads();
  for (int base = 0; base < n; base += 4096){
    int idx = base + tid*4;
    int4 v = make_int4(0,0,0,0);
    if (idx + 3 < n) v = *(const int4*)&cnt[idx];
    else {
      if (idx   < n) v.x = cnt[idx];
      if (idx+1 < n) v.y = cnt[idx+1];
      if (idx+2 < n) v.z = cnt[idx+2];
    }
    int s = v.x + v.y + v.z + v.w;
    int incl = s;
    #pragma unroll
    for (int o = 1; o < 64; o <<= 1){
      int t = __shfl_up(incl, o, 64);
      if (lane >= o) incl += t;
    }
    if (lane == 63) wtot[wid] = incl;
    __syncthreads();
    if (wid == 0){
      int w = (lane < 16) ? wtot[lane] : 0;
      #pragma unroll
      for (int o = 1; o < 16; o <<= 1){
        int t = __shfl_up(w, o, 64);
        if (lane >= o) w += t;
      }
      if (lane < 16) wtot[lane] = w;
    }
    __syncthreads();
    int pre = carry + (wid ? wtot[wid-1] : 0) + (incl - s);
    if (idx < n){
      cursor[idx] = pre; rowptr[idx+1] = pre + v.x; dis[idx] = rsqrtf((float)v.x + 1.0f);
      pre += v.x;
      if (idx+1 < n){
        cursor[idx+1] = pre; rowptr[idx+2] = pre + v.y; dis[idx+1] = rsqrtf((float)v.y + 1.0f);
        pre += v.y;
        if (idx+2 < n){
          cursor[idx+2] = pre; rowptr[idx+3] = pre + v.z; dis[idx+2] = rsqrtf((float)v.z + 1.0f);
          pre += v.z;
          if (idx+3 < n){
            cursor[idx+3] = pre; rowptr[idx+4] = pre + v.w; dis[idx+3] = rsqrtf((float)v.w + 1.0f);
          }
        }
      }
    }
    int total = wtot[15];
    __syncthreads();
    if (tid == 0) carry += total;
    __syncthreads();
  }
}

__global__ void k_fill(const int* __restrict__ src, const int* __restrict__ dst,
                       const float* __restrict__ dis, int* __restrict__ cursor,
                       int2* __restrict__ edata, int E){
  int e = blockIdx.x*256 + threadIdx.x;
  if (e >= E) return;
  int s = src[e], d = dst[e];
  int pos = atomicAdd(&cursor[d], 1);
  edata[pos] = make_int2(s, __float_as_int(dis[s]*dis[d]));
}

// pack W [128,128] fp32 -> fragment-major bf16 for mfma_f32_16x16x32_bf16 B-operand
__global__ void k_prepW(const float* __restrict__ W1, const float* __restrict__ W2,
                        const float* __restrict__ W3, ushort* __restrict__ Wf){
  const float* Ws[3] = {W1, W2, W3};
  int l = blockIdx.y;
  int idx = blockIdx.x*256 + threadIdx.x;        // 0..16383
  int k = idx >> 7, n = idx & 127;
  float w = Ws[l][idx];
  int kb = k >> 5, q = (k >> 3) & 3, j = k & 7;
  int nt = n >> 4, col = n & 15;
  Wf[(size_t)l*16384 + (((size_t)(kb*8 + nt)*64 + q*16 + col)*8 + j)] = f2bf(w);
}

// ------------------- GEMM: bf16 MFMA, fused BN-affine+ReLU on A -------------------
template<int MODE>
__global__ __launch_bounds__(256) void k_gemm(const float* __restrict__ A,
                                              const ushort* __restrict__ Wf,
                                              const float* __restrict__ sums,
                                              const float* __restrict__ g,
                                              const float* __restrict__ be,
                                              ushort* __restrict__ O, int n, float invN){
  __shared__ float aL[HD], bL[HD];
  int tid = threadIdx.x;
  if (MODE){
    if (tid < HD){
      float m = sums[tid]*invN;
      float var = fmaxf(sums[HD+tid]*invN - m*m, 0.f);
      float Ac = g[tid]*rsqrtf(var + EPS);
      aL[tid] = Ac; bL[tid] = be[tid] - m*Ac;
    }
    __syncthreads();
  }
  int lane = tid & 63, wave = tid >> 6;
  int quad = lane >> 4, r16 = lane & 15;
  int row = blockIdx.x*64 + wave*16 + r16;
  int rowc = min(row, n-1);
  const float* Arow = A + (size_t)rowc*HD;
  floatx4 acc[8] = {};
  #pragma unroll
  for (int kb = 0; kb < 4; ++kb){
    int k0 = kb*32 + quad*8;
    float4 x0 = *(const float4*)(Arow + k0);
    float4 x1 = *(const float4*)(Arow + k0 + 4);
    if (MODE){
      float4 ca0 = *(const float4*)(aL + k0), ca1 = *(const float4*)(aL + k0 + 4);
      float4 cb0 = *(const float4*)(bL + k0), cb1 = *(const float4*)(bL + k0 + 4);
      x0.x = fmaxf(x0.x*ca0.x + cb0.x, 0.f);
      x0.y = fmaxf(x0.y*ca0.y + cb0.y, 0.f);
      x0.z = fmaxf(x0.z*ca0.z + cb0.z, 0.f);
      x0.w = fmaxf(x0.w*ca0.w + cb0.w, 0.f);
      x1.x = fmaxf(x1.x*ca1.x + cb1.x, 0.f);
      x1.y = fmaxf(x1.y*ca1.y + cb1.y, 0.f);
      x1.z = fmaxf(x1.z*ca1.z + cb1.z, 0.f);
      x1.w = fmaxf(x1.w*ca1.w + cb1.w, 0.f);
    }
    short8 af;
    af[0] = (short)f2bf(x0.x); af[1] = (short)f2bf(x0.y);
    af[2] = (short)f2bf(x0.z); af[3] = (short)f2bf(x0.w);
    af[4] = (short)f2bf(x1.x); af[5] = (short)f2bf(x1.y);
    af[6] = (short)f2bf(x1.z); af[7] = (short)f2bf(x1.w);
    const ushort* wp = Wf + ((size_t)(kb*8)*64 + lane)*8;
    #pragma unroll
    for (int nt = 0; nt < 8; ++nt){
      short8 bf = *(const short8*)(wp + (size_t)nt*64*8);
      acc[nt] = __builtin_amdgcn_mfma_f32_16x16x32_bf16(af, bf, acc[nt], 0, 0, 0);
    }
  }
  int rbase = blockIdx.x*64 + wave*16 + quad*4;
  #pragma unroll
  for (int nt = 0; nt < 8; ++nt){
    #pragma unroll
    for (int r = 0; r < 4; ++r){
      int rr = rbase + r;
      if (rr < n) O[(size_t)rr*HD + nt*16 + r16] = f2bf(acc[nt][r]);
    }
  }
}

// ------------------- edge aggregation + fused BN-stats partials -------------------
// 16 lanes/node, 16 nodes/block. Per-block column partial sums/sumsq -> scratch row.
__global__ __launch_bounds__(256) void k_gather(const ushort* __restrict__ hw,
                                                const int* __restrict__ rowptr,
                                                const int2* __restrict__ edata,
                                                const float* __restrict__ dis,
                                                float* __restrict__ agg,
                                                float* __restrict__ scratch,
                                                float* __restrict__ sums, int N){
  __shared__ float2 sm[4][HD];
  if (blockIdx.x == 0) sums[threadIdx.x] = 0.f;   // zero before k_reduce's atomics
  int grp = threadIdx.x >> 4, j = threadIdx.x & 15;
  int wave = threadIdx.x >> 6, lane = threadIdx.x & 63;
  int i = blockIdx.x*16 + grp;
  bool valid = (i < N);
  int ic = valid ? i : N-1;
  float sn = dis[ic]; sn *= sn;
  uint4 q = ((const uint4*)(hw + (size_t)ic*HD))[j];
  float a[8];
  a[0] = bflo(q.x)*sn; a[1] = bfhi(q.x)*sn;
  a[2] = bflo(q.y)*sn; a[3] = bfhi(q.y)*sn;
  a[4] = bflo(q.z)*sn; a[5] = bfhi(q.z)*sn;
  a[6] = bflo(q.w)*sn; a[7] = bfhi(q.w)*sn;
  int e = rowptr[ic], e1 = rowptr[ic+1];
  #define ACC8(Q, W) \
    a[0] = fmaf(bflo(Q.x), W, a[0]); a[1] = fmaf(bfhi(Q.x), W, a[1]); \
    a[2] = fmaf(bflo(Q.y), W, a[2]); a[3] = fmaf(bfhi(Q.y), W, a[3]); \
    a[4] = fmaf(bflo(Q.z), W, a[4]); a[5] = fmaf(bfhi(Q.z), W, a[5]); \
    a[6] = fmaf(bflo(Q.w), W, a[6]); a[7] = fmaf(bfhi(Q.w), W, a[7]);
  for (; e + 4 <= e1; e += 4){
    int2 d0 = edata[e], d1 = edata[e+1], d2 = edata[e+2], d3 = edata[e+3];
    uint4 q0 = ((const uint4*)(hw + (size_t)d0.x*HD))[j];
    uint4 q1 = ((const uint4*)(hw + (size_t)d1.x*HD))[j];
    uint4 q2 = ((const uint4*)(hw + (size_t)d2.x*HD))[j];
    uint4 q3 = ((const uint4*)(hw + (size_t)d3.x*HD))[j];
    float w0 = __int_as_float(d0.y), w1 = __int_as_float(d1.y);
    float w2 = __int_as_float(d2.y), w3 = __int_as_float(d3.y);
    ACC8(q0, w0); ACC8(q1, w1); ACC8(q2, w2); ACC8(q3, w3);
  }
  for (; e < e1; ++e){
    int2 d = edata[e];
    uint4 qq = ((const uint4*)(hw + (size_t)d.x*HD))[j];
    float w = __int_as_float(d.y);
    ACC8(qq, w);
  }
  #undef ACC8
  if (valid){
    float* out = agg + (size_t)i*HD + j*8;
    *(float4*)out       = make_float4(a[0], a[1], a[2], a[3]);
    *(float4*)(out + 4) = make_float4(a[4], a[5], a[6], a[7]);
  }
  // fused stats: reduce (sum, sumsq) over the block's 16 nodes per channel
  float z = valid ? 1.f : 0.f;
  #pragma unroll
  for (int k = 0; k < 8; ++k){
    float s = a[k]*z, qq = a[k]*a[k]*z;
    s  += __shfl_xor(s, 16);  s  += __shfl_xor(s, 32);
    qq += __shfl_xor(qq, 16); qq += __shfl_xor(qq, 32);
    if (lane < 16) sm[wave][lane*8 + k] = make_float2(s, qq);
  }
  __syncthreads();
  int t = threadIdx.x;
  if (t < HD){
    float2 r0 = sm[0][t], r1 = sm[1][t], r2 = sm[2][t], r3 = sm[3][t];
    scratch[(size_t)blockIdx.x*256 + t]      = r0.x + r1.x + r2.x + r3.x;
    scratch[(size_t)blockIdx.x*256 + HD + t] = r0.y + r1.y + r2.y + r3.y;
  }
}

// coalesced second-stage reduction: sums[t] += sum over scratch rows
__global__ __launch_bounds__(256) void k_reduce(const float* __restrict__ scratch,
                                                float* __restrict__ sums, int R){
  int t = threadIdx.x;
  float acc = 0.f;
  for (int r = blockIdx.x; r < R; r += gridDim.x)
    acc += scratch[(size_t)r*256 + t];
  atomicAdd(&sums[t], acc);
}

// ------------------- mean pool (fused layer-3 BN+ReLU, fused counts) -------------------

__global__ __launch_bounds__(128) void k_pool(const float* __restrict__ h,
                                              const int* __restrict__ batch,
                                              const float* __restrict__ sums,
                                              const float* __restrict__ g,
                                              const float* __restrict__ be,
                                              float* __restrict__ pooled,
                                              float* __restrict__ cntf, int N, float invN){
  int c = threadIdx.x;
  float m = sums[c]*invN;
  float var = fmaxf(sums[HD+c]*invN - m*m, 0.f);
  float a = g[c]*rsqrtf(var + EPS);
  float b = be[c] - m*a;
  int start = blockIdx.x * 32;
  if (start >= N) return;
  int end = min(start + 32, N);
  int cur = batch[start];
  float acc = 0.f; int run = 0;
  for (int i = start; i < end; ++i){
    int bb = batch[i];
    if (bb != cur){
      atomicAdd(&pooled[(size_t)cur*HD + c], acc);
      if (c == 0) atomicAdd(&cntf[cur], (float)run);
      acc = 0.f; run = 0; cur = bb;
    }
    acc += fmaxf(h[(size_t)i*HD + c]*a + b, 0.f);
    run++;
  }
  atomicAdd(&pooled[(size_t)cur*HD + c], acc);
  if (c == 0) atomicAdd(&cntf[cur], (float)run);
}

// ------------------- FC head -------------------

__global__ __launch_bounds__(64) void k_fc1(const float* __restrict__ pooled,
                                            const float* __restrict__ cntf,
                                            const float* __restrict__ W,
                                            const float* __restrict__ b,
                                            float* __restrict__ z,
                                            float* __restrict__ sums2, int G){
  int g = blockIdx.x, j = threadIdx.x;
  if (g == 0){ sums2[j] = 0.f; sums2[FCD + j] = 0.f; }
  float inv = 1.0f / fmaxf(cntf[g], 1.0f);
  float acc = 0.f;
  for (int k = 0; k < HD; ++k)
    acc += pooled[(size_t)g*HD + k] * W[k*FCD + j];
  z[(size_t)g*FCD + j] = acc * inv + b[j];
}

__global__ __launch_bounds__(64) void k_stats2(const float* __restrict__ z,
                                               float* __restrict__ sums2, int G){
  int c = threadIdx.x;
  float s = 0.f, q = 0.f;
  for (int i = blockIdx.x; i < G; i += gridDim.x){
    float v = z[(size_t)i*FCD + c]; s += v; q += v*v;
  }
  atomicAdd(&sums2[c], s);
  atomicAdd(&sums2[FCD + c], q);
}

__global__ __launch_bounds__(64) void k_final(const float* __restrict__ z,
                                              const float* __restrict__ sums2,
                                              const float* __restrict__ g,
                                              const float* __restrict__ be,
                                              const float* __restrict__ w2,
                                              const float* __restrict__ b2,
                                              float* __restrict__ out, int G, float invG){
  int gg = blockIdx.x, c = threadIdx.x;
  float m = sums2[c]*invG;
  float var = fmaxf(sums2[FCD+c]*invG - m*m, 0.f);
  float A = g[c]*rsqrtf(var + EPS);
  float B = be[c] - m*A;
  float v = fmaxf(z[(size_t)gg*FCD + c]*A + B, 0.f) * w2[c];
  #pragma unroll
  for (int o = 32; o > 0; o >>= 1) v += __shfl_down(v, o, 64);
  if (c == 0) out[gg] = v + b2[0];
}

// ------------------- launch -------------------

extern "C" void kernel_launch(void* const* d_in, const int* in_sizes, int n_in,
                              void* d_out, int out_size, void* d_ws, size_t ws_size,
                              hipStream_t stream){
  const float* x    = (const float*)d_in[0];
  const int*   ei   = (const int*)d_in[1];
  const int*   batch= (const int*)d_in[2];
  const float* W1 = (const float*)d_in[3];
  const float* g1 = (const float*)d_in[5];
  const float* be1= (const float*)d_in[6];
  const float* W2 = (const float*)d_in[7];
  const float* g2 = (const float*)d_in[9];
  const float* be2= (const float*)d_in[10];
  const float* W3 = (const float*)d_in[11];
  const float* g3 = (const float*)d_in[13];
  const float* be3= (const float*)d_in[14];
  const float* fcW1 = (const float*)d_in[15];
  const float* fcb1 = (const float*)d_in[16];
  const float* fcg1 = (const float*)d_in[17];
  const float* fcbe1= (const float*)d_in[18];
  const float* fcW2 = (const float*)d_in[19];
  const float* fcb2 = (const float*)d_in[20];
  float* out = (float*)d_out;

  const int N = in_sizes[0] / HD;      // 50000
  const int E = in_sizes[1] / 2;       // 800000
  const int G = out_size;              // 500

  const int* esrc = ei;
  const int* edst = ei + E;

  char* p = (char*)d_ws;
  auto alloc = [&](size_t bytes)->void*{
    void* r = (void*)p; p += (bytes + 255) & ~(size_t)255; return r;
  };
  int gatherBlocks = (N + 15)/16;
  int*    cnt    = (int*)   alloc((size_t)N*4);
  int*    rowptr = (int*)   alloc((size_t)(N+1)*4);
  int*    cursor = (int*)   alloc((size_t)N*4);
  int2*   edata  = (int2*)  alloc((size_t)E*8);
  float*  dis    = (float*) alloc((size_t)N*4);
  ushort* HWb    = (ushort*)alloc((size_t)N*HD*2);
  float*  AGG    = (float*) alloc((size_t)N*HD*4);
  ushort* Wf     = (ushort*)alloc((size_t)3*HD*HD*2);
  float*  sums   = (float*) alloc(2*HD*4);
  float*  scratch= (float*) alloc((size_t)gatherBlocks*256*4);
  float*  pooled = (float*) alloc(((size_t)G*HD + G)*4);
  float*  cntf   = pooled + (size_t)G*HD;
  float*  zbuf   = (float*) alloc((size_t)G*FCD*4);
  float*  sums2  = (float*) alloc(2*FCD*4);

  int eb = (E + 255)/256;
  float invN = 1.0f/(float)N, invG = 1.0f/(float)G;

  // preprocessing
  hipMemsetAsync(cnt, 0, (size_t)N*4, stream);
  k_count<<<eb, 256, 0, stream>>>(edst, cnt, E);
  k_scan <<<1, 1024, 0, stream>>>(cnt, rowptr, cursor, dis, N);
  k_fill <<<eb, 256, 0, stream>>>(esrc, edst, dis, cursor, edata, E);
  k_prepW<<<dim3(64,3), 256, 0, stream>>>(W1, W2, W3, Wf);

  int gemmBlocks = (N + 63)/64;

  // layer 1
  k_gemm<0> <<<gemmBlocks, 256, 0, stream>>>(x,   Wf,         nullptr, nullptr, nullptr, HWb, N, invN);
  k_gather  <<<gatherBlocks, 256, 0, stream>>>(HWb, rowptr, edata, dis, AGG, scratch, sums, N);
  k_reduce  <<<64, 256, 0, stream>>>(scratch, sums, gatherBlocks);
  // layer 2 (BN1+ReLU fused into A-load)
  k_gemm<1> <<<gemmBlocks, 256, 0, stream>>>(AGG, Wf + 16384, sums, g1, be1, HWb, N, invN);
  k_gather  <<<gatherBlocks, 256, 0, stream>>>(HWb, rowptr, edata, dis, AGG, scratch, sums, N);
  k_reduce  <<<64, 256, 0, stream>>>(scratch, sums, gatherBlocks);
  // layer 3 (BN2+ReLU fused into A-load)
  k_gemm<1> <<<gemmBlocks, 256, 0, stream>>>(AGG, Wf + 32768, sums, g2, be2, HWb, N, invN);
  k_gather  <<<gatherBlocks, 256, 0, stream>>>(HWb, rowptr, edata, dis, AGG, scratch, sums, N);
  k_reduce  <<<64, 256, 0, stream>>>(scratch, sums, gatherBlocks);

  // pool (BN3+ReLU fused) + head
  hipMemsetAsync(pooled, 0, ((size_t)G*HD + G)*4, stream);
  k_pool  <<<(N+31)/32, 128, 0, stream>>>(AGG, batch, sums, g3, be3, pooled, cntf, N, invN);
  k_fc1   <<<G, FCD, 0, stream>>>(pooled, cntf, fcW1, fcb1, zbuf, sums2, G);
  k_stats2<<<64, FCD, 0, stream>>>(zbuf, sums2, G);
  k_final <<<G, FCD, 0, stream>>>(zbuf, sums2, fcg1, fcbe1, fcW2, fcb2, out, G, invG);
}

// Round 4
// 407.018 us; speedup vs baseline: 2.2742x; 1.0698x over previous
//
#include <hip/hip_runtime.h>

#define EPS 1e-5f
constexpr int HD = 128;   // node feature / hidden dim
constexpr int FCD = 64;   // fc hidden dim

typedef __attribute__((ext_vector_type(8))) short short8;
typedef __attribute__((ext_vector_type(4))) float floatx4;

// ---------- bf16 helpers ----------
__device__ inline ushort f2bf(float f){
  union{float f; unsigned u;} v; v.f = f;
  unsigned r = v.u + 0x7FFFu + ((v.u >> 16) & 1u);
  return (ushort)(r >> 16);
}
__device__ inline float bflo(unsigned u){ union{unsigned i; float f;} v; v.i = u << 16;        return v.f; }
__device__ inline float bfhi(unsigned u){ union{unsigned i; float f;} v; v.i = u & 0xFFFF0000u; return v.f; }
__device__ inline float bf2f(ushort u){ union{unsigned i; float f;} v; v.i = ((unsigned)u) << 16; return v.f; }

// ------------------- preprocessing -------------------

__global__ void k_count(const int* __restrict__ dst, int* __restrict__ cnt, int E){
  int e = blockIdx.x*256 + threadIdx.x;
  if (e < E) atomicAdd(&cnt[dst[e]], 1);
}

// chunk = 1024 elements (256 thr x int4). nChunks <= 64 assumed (N <= 65536).
__global__ __launch_bounds__(256) void k_chunksum(const int* __restrict__ cnt,
                                                  int* __restrict__ csum, int n){
  __shared__ int ws[4];
  int idx = blockIdx.x*1024 + threadIdx.x*4;
  int4 v = make_int4(0,0,0,0);
  if (idx + 3 < n) v = *(const int4*)&cnt[idx];
  else {
    if (idx   < n) v.x = cnt[idx];
    if (idx+1 < n) v.y = cnt[idx+1];
    if (idx+2 < n) v.z = cnt[idx+2];
  }
  int s = v.x + v.y + v.z + v.w;
  #pragma unroll
  for (int o = 1; o < 64; o <<= 1) s += __shfl_xor(s, o, 64);
  int lane = threadIdx.x & 63, wave = threadIdx.x >> 6;
  if (lane == 0) ws[wave] = s;
  __syncthreads();
  if (threadIdx.x == 0) csum[blockIdx.x] = ws[0]+ws[1]+ws[2]+ws[3];
}

__global__ __launch_bounds__(256) void k_scan2(const int* __restrict__ cnt,
                                               const int* __restrict__ csum,
                                               int* __restrict__ rowptr,
                                               int* __restrict__ cursor,
                                               float* __restrict__ dis, int n){
  __shared__ int sOff;
  __shared__ int wtot[4];
  int chunk = blockIdx.x;
  int tid = threadIdx.x, lane = tid & 63, wave = tid >> 6;
  if (wave == 0){
    int v = (lane < chunk) ? csum[lane] : 0;
    #pragma unroll
    for (int o = 1; o < 64; o <<= 1) v += __shfl_xor(v, o, 64);
    if (lane == 0) sOff = v;
  }
  int idx = chunk*1024 + tid*4;
  int4 v = make_int4(0,0,0,0);
  if (idx + 3 < n) v = *(const int4*)&cnt[idx];
  else {
    if (idx   < n) v.x = cnt[idx];
    if (idx+1 < n) v.y = cnt[idx+1];
    if (idx+2 < n) v.z = cnt[idx+2];
  }
  int s = v.x + v.y + v.z + v.w;
  int incl = s;
  #pragma unroll
  for (int o = 1; o < 64; o <<= 1){
    int t = __shfl_up(incl, o, 64);
    if (lane >= o) incl += t;
  }
  if (lane == 63) wtot[wave] = incl;
  __syncthreads();
  int woff = 0;
  for (int w = 0; w < wave; ++w) woff += wtot[w];
  int pre = sOff + woff + (incl - s);
  if (idx < n){
    if (idx == 0) rowptr[0] = 0;
    cursor[idx] = pre; rowptr[idx+1] = pre + v.x; dis[idx] = rsqrtf((float)v.x + 1.0f);
    pre += v.x;
    if (idx+1 < n){
      cursor[idx+1] = pre; rowptr[idx+2] = pre + v.y; dis[idx+1] = rsqrtf((float)v.y + 1.0f);
      pre += v.y;
      if (idx+2 < n){
        cursor[idx+2] = pre; rowptr[idx+3] = pre + v.z; dis[idx+2] = rsqrtf((float)v.z + 1.0f);
        pre += v.z;
        if (idx+3 < n){
          cursor[idx+3] = pre; rowptr[idx+4] = pre + v.w; dis[idx+3] = rsqrtf((float)v.w + 1.0f);
        }
      }
    }
  }
}

__global__ void k_fill(const int* __restrict__ src, const int* __restrict__ dst,
                       const float* __restrict__ dis, int* __restrict__ cursor,
                       int2* __restrict__ edata, int E){
  int e = blockIdx.x*256 + threadIdx.x;
  if (e >= E) return;
  int s = src[e], d = dst[e];
  int pos = atomicAdd(&cursor[d], 1);
  edata[pos] = make_int2(s, __float_as_int(dis[s]*dis[d]));
}

// pack W [128,128] fp32 -> fragment-major bf16 for mfma_f32_16x16x32_bf16 B-operand
__global__ void k_prepW(const float* __restrict__ W1, const float* __restrict__ W2,
                        const float* __restrict__ W3, ushort* __restrict__ Wf){
  const float* Ws[3] = {W1, W2, W3};
  int l = blockIdx.y;
  int idx = blockIdx.x*256 + threadIdx.x;        // 0..16383
  int k = idx >> 7, n = idx & 127;
  float w = Ws[l][idx];
  int kb = k >> 5, q = (k >> 3) & 3, j = k & 7;
  int nt = n >> 4, col = n & 15;
  Wf[(size_t)l*16384 + (((size_t)(kb*8 + nt)*64 + q*16 + col)*8 + j)] = f2bf(w);
}

// ------------------- GEMM: bf16 MFMA, fused BN-affine+ReLU on A -------------------
// MODE 0: A fp32 (= x), plain convert. MODE 1: A bf16 (= AGG), affine+relu in fp32.
template<int MODE>
__global__ __launch_bounds__(256) void k_gemm(const void* __restrict__ Av,
                                              const ushort* __restrict__ Wf,
                                              const float* __restrict__ sums,
                                              const float* __restrict__ g,
                                              const float* __restrict__ be,
                                              ushort* __restrict__ O, int n, float invN){
  __shared__ float aL[HD], bL[HD];
  int tid = threadIdx.x;
  if (MODE){
    if (tid < HD){
      float m = sums[tid]*invN;
      float var = fmaxf(sums[HD+tid]*invN - m*m, 0.f);
      float Ac = g[tid]*rsqrtf(var + EPS);
      aL[tid] = Ac; bL[tid] = be[tid] - m*Ac;
    }
    __syncthreads();
  }
  int lane = tid & 63, wave = tid >> 6;
  int quad = lane >> 4, r16 = lane & 15;
  int row = blockIdx.x*64 + wave*16 + r16;
  int rowc = min(row, n-1);
  floatx4 acc[8] = {};
  #pragma unroll
  for (int kb = 0; kb < 4; ++kb){
    int k0 = kb*32 + quad*8;
    short8 af;
    if (MODE){
      const ushort* Arow = (const ushort*)Av + (size_t)rowc*HD;
      short8 raw = *(const short8*)(Arow + k0);
      #pragma unroll
      for (int jj = 0; jj < 8; ++jj){
        float f = bf2f((ushort)raw[jj]);
        f = fmaxf(f*aL[k0+jj] + bL[k0+jj], 0.f);
        af[jj] = (short)f2bf(f);
      }
    } else {
      const float* Arow = (const float*)Av + (size_t)rowc*HD;
      float4 x0 = *(const float4*)(Arow + k0);
      float4 x1 = *(const float4*)(Arow + k0 + 4);
      af[0] = (short)f2bf(x0.x); af[1] = (short)f2bf(x0.y);
      af[2] = (short)f2bf(x0.z); af[3] = (short)f2bf(x0.w);
      af[4] = (short)f2bf(x1.x); af[5] = (short)f2bf(x1.y);
      af[6] = (short)f2bf(x1.z); af[7] = (short)f2bf(x1.w);
    }
    const ushort* wp = Wf + ((size_t)(kb*8)*64 + lane)*8;
    #pragma unroll
    for (int nt = 0; nt < 8; ++nt){
      short8 bf = *(const short8*)(wp + (size_t)nt*64*8);
      acc[nt] = __builtin_amdgcn_mfma_f32_16x16x32_bf16(af, bf, acc[nt], 0, 0, 0);
    }
  }
  int rbase = blockIdx.x*64 + wave*16 + quad*4;
  #pragma unroll
  for (int nt = 0; nt < 8; ++nt){
    #pragma unroll
    for (int r = 0; r < 4; ++r){
      int rr = rbase + r;
      if (rr < n) O[(size_t)rr*HD + nt*16 + r16] = f2bf(acc[nt][r]);
    }
  }
}

// ------------------- edge aggregation + fused BN-stats partials -------------------
// 16 lanes/node, 16 nodes/block; prefetched int4 edata pairs; bf16 AGG output;
// stats taken from fp32 accumulators (exact).
__global__ __launch_bounds__(256) void k_gather(const ushort* __restrict__ hw,
                                                const int* __restrict__ rowptr,
                                                const int2* __restrict__ edata,
                                                const float* __restrict__ dis,
                                                ushort* __restrict__ agg,
                                                float* __restrict__ scratch,
                                                float* __restrict__ sums, int N){
  __shared__ float2 sm[4][HD];
  if (blockIdx.x == 0) sums[threadIdx.x] = 0.f;   // zero before k_reduce's atomics
  int grp = threadIdx.x >> 4, j = threadIdx.x & 15;
  int wave = threadIdx.x >> 6, lane = threadIdx.x & 63;
  int i = blockIdx.x*16 + grp;
  bool valid = (i < N);
  int ic = valid ? i : N-1;
  float sn = dis[ic]; sn *= sn;
  uint4 q = ((const uint4*)(hw + (size_t)ic*HD))[j];
  float a[8];
  a[0] = bflo(q.x)*sn; a[1] = bfhi(q.x)*sn;
  a[2] = bflo(q.y)*sn; a[3] = bfhi(q.y)*sn;
  a[4] = bflo(q.z)*sn; a[5] = bfhi(q.z)*sn;
  a[6] = bflo(q.w)*sn; a[7] = bfhi(q.w)*sn;
  int e = rowptr[ic], e1 = rowptr[ic+1];
  #define ACC8(Q, W) \
    a[0] = fmaf(bflo(Q.x), W, a[0]); a[1] = fmaf(bfhi(Q.x), W, a[1]); \
    a[2] = fmaf(bflo(Q.y), W, a[2]); a[3] = fmaf(bfhi(Q.y), W, a[3]); \
    a[4] = fmaf(bflo(Q.z), W, a[4]); a[5] = fmaf(bfhi(Q.z), W, a[5]); \
    a[6] = fmaf(bflo(Q.w), W, a[6]); a[7] = fmaf(bfhi(Q.w), W, a[7]);
  // head: make e even so int4 loads are 16B-aligned
  if (e < e1 && (e & 1)){
    int2 d = edata[e];
    uint4 qq = ((const uint4*)(hw + (size_t)d.x*HD))[j];
    ACC8(qq, __int_as_float(d.y));
    e++;
  }
  int4 c0, c1;
  if (e + 4 <= e1){
    c0 = *(const int4*)&edata[e];
    c1 = *(const int4*)&edata[e+2];
  }
  while (e + 4 <= e1){
    int en = e + 4;
    int4 n0, n1;
    if (en + 4 <= e1){                     // prefetch next 4 edges
      n0 = *(const int4*)&edata[en];
      n1 = *(const int4*)&edata[en+2];
    }
    uint4 q0 = ((const uint4*)(hw + (size_t)c0.x*HD))[j];
    uint4 q1 = ((const uint4*)(hw + (size_t)c0.z*HD))[j];
    uint4 q2 = ((const uint4*)(hw + (size_t)c1.x*HD))[j];
    uint4 q3 = ((const uint4*)(hw + (size_t)c1.z*HD))[j];
    ACC8(q0, __int_as_float(c0.y)); ACC8(q1, __int_as_float(c0.w));
    ACC8(q2, __int_as_float(c1.y)); ACC8(q3, __int_as_float(c1.w));
    c0 = n0; c1 = n1; e = en;
  }
  for (; e < e1; ++e){
    int2 d = edata[e];
    uint4 qq = ((const uint4*)(hw + (size_t)d.x*HD))[j];
    ACC8(qq, __int_as_float(d.y));
  }
  #undef ACC8
  if (valid){
    uint4 o;
    o.x = (unsigned)f2bf(a[0]) | ((unsigned)f2bf(a[1]) << 16);
    o.y = (unsigned)f2bf(a[2]) | ((unsigned)f2bf(a[3]) << 16);
    o.z = (unsigned)f2bf(a[4]) | ((unsigned)f2bf(a[5]) << 16);
    o.w = (unsigned)f2bf(a[6]) | ((unsigned)f2bf(a[7]) << 16);
    ((uint4*)(agg + (size_t)i*HD))[j] = o;
  }
  // fused stats
  float z = valid ? 1.f : 0.f;
  #pragma unroll
  for (int k = 0; k < 8; ++k){
    float s = a[k]*z, qq = a[k]*a[k]*z;
    s  += __shfl_xor(s, 16);  s  += __shfl_xor(s, 32);
    qq += __shfl_xor(qq, 16); qq += __shfl_xor(qq, 32);
    if (lane < 16) sm[wave][lane*8 + k] = make_float2(s, qq);
  }
  __syncthreads();
  int t = threadIdx.x;
  if (t < HD){
    float2 r0 = sm[0][t], r1 = sm[1][t], r2 = sm[2][t], r3 = sm[3][t];
    scratch[(size_t)blockIdx.x*256 + t]      = r0.x + r1.x + r2.x + r3.x;
    scratch[(size_t)blockIdx.x*256 + HD + t] = r0.y + r1.y + r2.y + r3.y;
  }
}

// coalesced second-stage reduction
__global__ __launch_bounds__(256) void k_reduce(const float* __restrict__ scratch,
                                                float* __restrict__ sums, int R){
  int t = threadIdx.x;
  float acc = 0.f;
  for (int r = blockIdx.x; r < R; r += gridDim.x)
    acc += scratch[(size_t)r*256 + t];
  atomicAdd(&sums[t], acc);
}

// ------------------- mean pool (fused layer-3 BN+ReLU, fused counts) -------------------

__global__ __launch_bounds__(128) void k_pool(const ushort* __restrict__ h,
                                              const int* __restrict__ batch,
                                              const float* __restrict__ sums,
                                              const float* __restrict__ g,
                                              const float* __restrict__ be,
                                              float* __restrict__ pooled,
                                              float* __restrict__ cntf, int N, float invN){
  int c = threadIdx.x;
  float m = sums[c]*invN;
  float var = fmaxf(sums[HD+c]*invN - m*m, 0.f);
  float a = g[c]*rsqrtf(var + EPS);
  float b = be[c] - m*a;
  int start = blockIdx.x * 32;
  if (start >= N) return;
  int end = min(start + 32, N);
  int cur = batch[start];
  float acc = 0.f; int run = 0;
  for (int i = start; i < end; ++i){
    int bb = batch[i];
    if (bb != cur){
      atomicAdd(&pooled[(size_t)cur*HD + c], acc);
      if (c == 0) atomicAdd(&cntf[cur], (float)run);
      acc = 0.f; run = 0; cur = bb;
    }
    acc += fmaxf(bf2f(h[(size_t)i*HD + c])*a + b, 0.f);
    run++;
  }
  atomicAdd(&pooled[(size_t)cur*HD + c], acc);
  if (c == 0) atomicAdd(&cntf[cur], (float)run);
}

// ------------------- FC head -------------------

__global__ __launch_bounds__(64) void k_fc1(const float* __restrict__ pooled,
                                            const float* __restrict__ cntf,
                                            const float* __restrict__ W,
                                            const float* __restrict__ b,
                                            float* __restrict__ z,
                                            float* __restrict__ sums2, int G){
  int g = blockIdx.x, j = threadIdx.x;
  if (g == 0){ sums2[j] = 0.f; sums2[FCD + j] = 0.f; }
  float inv = 1.0f / fmaxf(cntf[g], 1.0f);
  float acc = 0.f;
  for (int k = 0; k < HD; ++k)
    acc += pooled[(size_t)g*HD + k] * W[k*FCD + j];
  z[(size_t)g*FCD + j] = acc * inv + b[j];
}

__global__ __launch_bounds__(64) void k_stats2(const float* __restrict__ z,
                                               float* __restrict__ sums2, int G){
  int c = threadIdx.x;
  float s = 0.f, q = 0.f;
  for (int i = blockIdx.x; i < G; i += gridDim.x){
    float v = z[(size_t)i*FCD + c]; s += v; q += v*v;
  }
  atomicAdd(&sums2[c], s);
  atomicAdd(&sums2[FCD + c], q);
}

__global__ __launch_bounds__(64) void k_final(const float* __restrict__ z,
                                              const float* __restrict__ sums2,
                                              const float* __restrict__ g,
                                              const float* __restrict__ be,
                                              const float* __restrict__ w2,
                                              const float* __restrict__ b2,
                                              float* __restrict__ out, int G, float invG){
  int gg = blockIdx.x, c = threadIdx.x;
  float m = sums2[c]*invG;
  float var = fmaxf(sums2[FCD+c]*invG - m*m, 0.f);
  float A = g[c]*rsqrtf(var + EPS);
  float B = be[c] - m*A;
  float v = fmaxf(z[(size_t)gg*FCD + c]*A + B, 0.f) * w2[c];
  #pragma unroll
  for (int o = 32; o > 0; o >>= 1) v += __shfl_down(v, o, 64);
  if (c == 0) out[gg] = v + b2[0];
}

// ------------------- launch -------------------

extern "C" void kernel_launch(void* const* d_in, const int* in_sizes, int n_in,
                              void* d_out, int out_size, void* d_ws, size_t ws_size,
                              hipStream_t stream){
  const float* x    = (const float*)d_in[0];
  const int*   ei   = (const int*)d_in[1];
  const int*   batch= (const int*)d_in[2];
  const float* W1 = (const float*)d_in[3];
  const float* g1 = (const float*)d_in[5];
  const float* be1= (const float*)d_in[6];
  const float* W2 = (const float*)d_in[7];
  const float* g2 = (const float*)d_in[9];
  const float* be2= (const float*)d_in[10];
  const float* W3 = (const float*)d_in[11];
  const float* g3 = (const float*)d_in[13];
  const float* be3= (const float*)d_in[14];
  const float* fcW1 = (const float*)d_in[15];
  const float* fcb1 = (const float*)d_in[16];
  const float* fcg1 = (const float*)d_in[17];
  const float* fcbe1= (const float*)d_in[18];
  const float* fcW2 = (const float*)d_in[19];
  const float* fcb2 = (const float*)d_in[20];
  float* out = (float*)d_out;

  const int N = in_sizes[0] / HD;      // 50000
  const int E = in_sizes[1] / 2;       // 800000
  const int G = out_size;              // 500

  const int* esrc = ei;
  const int* edst = ei + E;

  char* p = (char*)d_ws;
  auto alloc = [&](size_t bytes)->void*{
    void* r = (void*)p; p += (bytes + 255) & ~(size_t)255; return r;
  };
  int gatherBlocks = (N + 15)/16;
  int nChunks = (N + 1023)/1024;       // 49 (<= 64 required by k_scan2)
  int*    cnt    = (int*)   alloc((size_t)N*4);
  int*    rowptr = (int*)   alloc((size_t)(N+1)*4);
  int*    cursor = (int*)   alloc((size_t)N*4);
  int*    csum   = (int*)   alloc((size_t)nChunks*4);
  int2*   edata  = (int2*)  alloc((size_t)E*8);
  float*  dis    = (float*) alloc((size_t)N*4);
  ushort* HWb    = (ushort*)alloc((size_t)N*HD*2);
  ushort* AGG    = (ushort*)alloc((size_t)N*HD*2);
  ushort* Wf     = (ushort*)alloc((size_t)3*HD*HD*2);
  float*  sums   = (float*) alloc(2*HD*4);
  float*  scratch= (float*) alloc((size_t)gatherBlocks*256*4);
  float*  pooled = (float*) alloc(((size_t)G*HD + G)*4);
  float*  cntf   = pooled + (size_t)G*HD;
  float*  zbuf   = (float*) alloc((size_t)G*FCD*4);
  float*  sums2  = (float*) alloc(2*FCD*4);

  int eb = (E + 255)/256;
  float invN = 1.0f/(float)N, invG = 1.0f/(float)G;

  // preprocessing
  hipMemsetAsync(cnt, 0, (size_t)N*4, stream);
  k_count   <<<eb, 256, 0, stream>>>(edst, cnt, E);
  k_chunksum<<<nChunks, 256, 0, stream>>>(cnt, csum, N);
  k_scan2   <<<nChunks, 256, 0, stream>>>(cnt, csum, rowptr, cursor, dis, N);
  k_fill    <<<eb, 256, 0, stream>>>(esrc, edst, dis, cursor, edata, E);
  k_prepW   <<<dim3(64,3), 256, 0, stream>>>(W1, W2, W3, Wf);

  int gemmBlocks = (N + 63)/64;

  // layer 1
  k_gemm<0> <<<gemmBlocks, 256, 0, stream>>>(x,   Wf,         nullptr, nullptr, nullptr, HWb, N, invN);
  k_gather  <<<gatherBlocks, 256, 0, stream>>>(HWb, rowptr, edata, dis, AGG, scratch, sums, N);
  k_reduce  <<<64, 256, 0, stream>>>(scratch, sums, gatherBlocks);
  // layer 2 (BN1+ReLU fused into A-load)
  k_gemm<1> <<<gemmBlocks, 256, 0, stream>>>(AGG, Wf + 16384, sums, g1, be1, HWb, N, invN);
  k_gather  <<<gatherBlocks, 256, 0, stream>>>(HWb, rowptr, edata, dis, AGG, scratch, sums, N);
  k_reduce  <<<64, 256, 0, stream>>>(scratch, sums, gatherBlocks);
  // layer 3 (BN2+ReLU fused into A-load)
  k_gemm<1> <<<gemmBlocks, 256, 0, stream>>>(AGG, Wf + 32768, sums, g2, be2, HWb, N, invN);
  k_gather  <<<gatherBlocks, 256, 0, stream>>>(HWb, rowptr, edata, dis, AGG, scratch, sums, N);
  k_reduce  <<<64, 256, 0, stream>>>(scratch, sums, gatherBlocks);

  // pool (BN3+ReLU fused) + head
  hipMemsetAsync(pooled, 0, ((size_t)G*HD + G)*4, stream);
  k_pool  <<<(N+31)/32, 128, 0, stream>>>(AGG, batch, sums, g3, be3, pooled, cntf, N, invN);
  k_fc1   <<<G, FCD, 0, stream>>>(pooled, cntf, fcW1, fcb1, zbuf, sums2, G);
  k_stats2<<<64, FCD, 0, stream>>>(zbuf, sums2, G);
  k_final <<<G, FCD, 0, stream>>>(zbuf, sums2, fcg1, fcbe1, fcW2, fcb2, out, G, invG);
}